// Round 4
// baseline (2085.809 us; speedup 1.0000x reference)
//
#include <hip/hip_runtime.h>

#define S_STEPS 1024
#define BATCH 128
#define NQ 8

// Compressed xw: only wire-planes {0,1,5,6,7} per gate are ever read by seq.
// Layout: xw[((b*4+g)*5 + widx)*1024 + t], 128*20*1024 floats = 10.49 MB.
#define XW_COMPRESSED_FLOATS (BATCH * 20 * 1024)
#define CNT_BYTE_OFFSET ((size_t)XW_COMPRESSED_FLOATS * 4)   // 10,485,760

using v2f     = float __attribute__((ext_vector_type(2)));
using frag_ab = __attribute__((ext_vector_type(8))) short;   // 8 bf16
using frag_cd = __attribute__((ext_vector_type(4))) float;   // 4 fp32

#define INV2PI 0.15915494309189535f

// ---- helpers -----------------------------------------------------------
template<int CTRL>
__device__ __forceinline__ float dppf(float x) {   // DPP move (quad_perm / mirror / half_mirror)
  return __int_as_float(__builtin_amdgcn_update_dpp(0, __float_as_int(x), CTRL, 0xf, 0xf, true));
}
__device__ __forceinline__ short f2bf(float f) {   // fp32 -> bf16 (RNE)
  unsigned u = __float_as_uint(f);
  return (short)((u + 0x7FFFu + ((u >> 16) & 1u)) >> 16);
}
__device__ __forceinline__ float bf2f(short h) {
  return __uint_as_float(((unsigned)(unsigned short)h) << 16);
}

// xw data ops: relaxed AGENT-scope atomics -> sc0/sc1 dword ops that go to the
// MALL coherence point. Per-XCD L2s are NOT cross-coherent (G16); R3 showed
// plain stores + fences are not reliably visible across XCDs. Data itself now
// bypasses the non-coherent tiers; the flag provides ordering only.
__device__ __forceinline__ void st_xw(float* p, float v) {
  __hip_atomic_store((unsigned*)p, __float_as_uint(v),
                     __ATOMIC_RELAXED, __HIP_MEMORY_SCOPE_AGENT);
}
__device__ __forceinline__ float4 ld4_xw(const float4* p) {
  const unsigned* u = (const unsigned*)p;
  float4 r;
  r.x = __uint_as_float(__hip_atomic_load(u + 0, __ATOMIC_RELAXED, __HIP_MEMORY_SCOPE_AGENT));
  r.y = __uint_as_float(__hip_atomic_load(u + 1, __ATOMIC_RELAXED, __HIP_MEMORY_SCOPE_AGENT));
  r.z = __uint_as_float(__hip_atomic_load(u + 2, __ATOMIC_RELAXED, __HIP_MEMORY_SCOPE_AGENT));
  r.w = __uint_as_float(__hip_atomic_load(u + 3, __ATOMIC_RELAXED, __HIP_MEMORY_SCOPE_AGENT));
  return r;
}
__device__ __forceinline__ void wait_slice(const unsigned* cnt, int s) {
  while (__hip_atomic_load(&cnt[s], __ATOMIC_ACQUIRE, __HIP_MEMORY_SCOPE_AGENT) < 128u)
    __builtin_amdgcn_s_sleep(1);
}

// ---- fused kernel ------------------------------------------------------
// blocks 0..31   : consumer (seq recurrence), threads 0..63 active, no LDS.
// blocks 32..8223: producer (MFMA GEMM tile (b,t0)), pid = t0idx*128 + b so
//                  production order is t-ascending. Handshake: per-t0-slice
//                  counter, release-add by producer, acquire-poll by consumer.
__global__ __launch_bounds__(512) void qlstm_fused(
    const float* __restrict__ x,
    const float* __restrict__ Wf, const float* __restrict__ bf_,
    const float* __restrict__ Wi, const float* __restrict__ bi,
    const float* __restrict__ Wu, const float* __restrict__ bu,
    const float* __restrict__ Wo, const float* __restrict__ bo,
    float* __restrict__ xw, unsigned* __restrict__ cnt,
    float* __restrict__ out)
{
  if (blockIdx.x >= 32) {
    // ================= producer: one (b, t0) 16t x 32c tile =================
    __shared__ float xbuf[16 * 256];   // 16 KB, 16B-slot swizzled
    __shared__ float red[8 * 520];     // 16.6 KB reduction planes (pitch 520)

    const int tid  = threadIdx.x;
    const int lane = tid & 63;
    const int wid  = tid >> 6;               // 0..7 = k-slice (wid*32 .. +32)
    const int pid  = blockIdx.x - 32;        // 0..8191
    const int t0i  = pid >> 7;               // 0..63  (t-slice index)
    const int b    = pid & 127;              // 0..127
    const int t0   = t0i << 4;

    // coalesced x row load: thread T covers row r=T>>5, two 16B at slots s, 32+s
    {
      const int r = tid >> 5, s = tid & 31;
      const float* xrow = x + ((size_t)(t0 + r) * 128 + b) * 256;
      float4 f0 = *(const float4*)(xrow + s * 4);
      float4 f1 = *(const float4*)(xrow + 128 + s * 4);
      *(float4*)&xbuf[r * 256 + 4 * ((s)      ^ (r & 7))] = f0;
      *(float4*)&xbuf[r * 256 + 4 * ((32 + s) ^ (r & 7))] = f1;
    }

    // W fragments for this wave's k-slice (L2-resident, convert once)
    const int m  = lane & 15;                // A-row (c within n-tile) / t offset
    const int kg = lane >> 4;                // k group
    frag_ab awh[2], awl[2];
#pragma unroll
    for (int n = 0; n < 2; ++n) {
      const int c = n * 16 + m;
      const int g = c >> 3, w = c & 7;
      const float* Wg = (g == 0) ? Wf : (g == 1) ? Wi : (g == 2) ? Wu : Wo;
      const float* p = Wg + w * 264 + wid * 32 + kg * 8;
      float4 a  = *(const float4*)(p);
      float4 bq = *(const float4*)(p + 4);
      float vv[8] = {a.x, a.y, a.z, a.w, bq.x, bq.y, bq.z, bq.w};
#pragma unroll
      for (int j = 0; j < 8; ++j) {
        float wv = vv[j] * INV2PI;
        short h = f2bf(wv);
        awh[n][j] = h;
        awl[n][j] = f2bf(wv - bf2f(h));
      }
    }

    __syncthreads();

    // x fragment from LDS (same swizzle), convert, 6 MFMA (bf16 hi/lo split)
    float4 v0 = *(const float4*)&xbuf[m * 256 + 4 * ((wid * 8 + kg * 2)     ^ (m & 7))];
    float4 v1 = *(const float4*)&xbuf[m * 256 + 4 * ((wid * 8 + kg * 2 + 1) ^ (m & 7))];
    float xf[8] = {v0.x, v0.y, v0.z, v0.w, v1.x, v1.y, v1.z, v1.w};
    frag_ab xh, xl;
#pragma unroll
    for (int j = 0; j < 8; ++j) {
      short h = f2bf(xf[j]);
      xh[j] = h;
      xl[j] = f2bf(xf[j] - bf2f(h));
    }

    frag_cd acc0 = {0.f, 0.f, 0.f, 0.f};
    frag_cd acc1 = {0.f, 0.f, 0.f, 0.f};
    acc0 = __builtin_amdgcn_mfma_f32_16x16x32_bf16(awh[0], xh, acc0, 0, 0, 0);
    acc0 = __builtin_amdgcn_mfma_f32_16x16x32_bf16(awl[0], xh, acc0, 0, 0, 0);
    acc0 = __builtin_amdgcn_mfma_f32_16x16x32_bf16(awh[0], xl, acc0, 0, 0, 0);
    acc1 = __builtin_amdgcn_mfma_f32_16x16x32_bf16(awh[1], xh, acc1, 0, 0, 0);
    acc1 = __builtin_amdgcn_mfma_f32_16x16x32_bf16(awl[1], xh, acc1, 0, 0, 0);
    acc1 = __builtin_amdgcn_mfma_f32_16x16x32_bf16(awh[1], xl, acc1, 0, 0, 0);

    // cross-wave K reduction: red[v=n*4+rho][wid][lane]
#pragma unroll
    for (int rho = 0; rho < 4; ++rho) {
      red[(rho)     * 520 + wid * 64 + lane] = acc0[rho];
      red[(4 + rho) * 520 + wid * 64 + lane] = acc1[rho];
    }
    __syncthreads();

    // reduce + bias + compressed store (only wire-planes {0,1,5,6,7})
    {
      const int c  = tid >> 4, mm = tid & 15;
      const int v  = ((c >> 4) << 2) | (c & 3);          // n*4 + rho
      const int lp = (((c >> 2) & 3) << 4) | mm;         // kg*16 + m
      float sum = 0.f;
#pragma unroll
      for (int w8 = 0; w8 < 8; ++w8)
        sum += red[v * 520 + w8 * 64 + lp];
      const int g = c >> 3, w = c & 7;
      const int widx = (w==0)?0:(w==1)?1:(w==5)?2:(w==6)?3:(w==7)?4:-1;
      if (widx >= 0) {
        const float* bg = (g == 0) ? bf_ : (g == 1) ? bi : (g == 2) ? bu : bo;
        st_xw(&xw[((size_t)((b * 4 + g) * 5 + widx)) * 1024 + t0 + mm],
              sum + bg[w] * INV2PI);
      }
    }

    // signal: atomic data stores complete before barrier; then release the slice
    __threadfence();
    __syncthreads();
    if (tid == 0)
      __hip_atomic_fetch_add(&cnt[t0i], 1u, __ATOMIC_RELEASE, __HIP_MEMORY_SCOPE_AGENT);
    return;
  }

  // ================= consumer: recurrence (unchanged compute) =================
  if (threadIdx.x >= 64) return;

  const int lane = threadIdx.x;
  const int r = lane & 15, g = r >> 2, k = r & 3;
  const int b = blockIdx.x * 4 + (lane >> 4);
  const int B6 = (k >> 1) & 1, B7 = k & 1;
  const bool isB7 = (B7 != 0);
  const float s6 = B6 ? -1.f : 1.f,        o6 = B6 ? 1.f : 0.f;
  const float s7 = (B7^B6) ? -1.f : 1.f,   o7 = (B7^B6) ? 1.f : 0.f;
  const int wA = (k == 0) ? 0 : (k == 1) ? 5 : 7;        // W rows (uncompressed)
  const int wB = (k == 0) ? 1 : (k == 1) ? 6 : 7;
  const int widxA = (k == 0) ? 0 : (k == 1) ? 2 : 4;     // compressed xw planes
  const int widxB = (k == 0) ? 1 : (k == 1) ? 3 : 4;
  const bool g0 = (g & 1) != 0;
  const bool g1 = (g & 2) != 0;

  const float* Wg = (g == 0) ? Wf : (g == 1) ? Wi : (g == 2) ? Wu : Wo;
  v2f whA2[4], whB2[4];
#pragma unroll
  for (int j2 = 0; j2 < 4; ++j2) {
    whA2[j2] = (v2f){Wg[wA*264+256+2*j2] * INV2PI, Wg[wA*264+256+2*j2+1] * INV2PI};
    whB2[j2] = (v2f){Wg[wB*264+256+2*j2] * INV2PI, Wg[wB*264+256+2*j2+1] * INV2PI};
  }

  v2f h2[4];
#pragma unroll
  for (int j = 0; j < 4; ++j) h2[j] = (v2f){0.f, 0.f};
  float cA = 0.f, cB = 0.f, hqA = 0.f, hqB = 0.f;

  const float* bxw = xw + (size_t)b * 20480;
  const float4* pA = (const float4*)(bxw + (size_t)(g * 5 + widxA) * 1024);
  const float4* pB = (const float4*)(bxw + (size_t)(g * 5 + widxB) * 1024);

  wait_slice(cnt, 0);                       // prologue reads t<=7
  float4 curA = ld4_xw(pA + 0), nxtA = ld4_xw(pA + 1);
  float4 curB = ld4_xw(pB + 0), nxtB = ld4_xw(pB + 1);

  const int soff = b * 8 + r;     // valid for r<8 (= g*4+k)
  float houtS[16];

#pragma unroll 1
  for (int Tb = 0; Tb < S_STEPS; Tb += 16) {
    {                                       // this iter prefetches up to t=Tb+23
      int s = (Tb >> 4) + 1; if (s > 63) s = 63;
      wait_slice(cnt, s);
    }
#pragma unroll
    for (int sg = 0; sg < 4; ++sg) {
      int gi = (Tb >> 2) + sg;
      int tp = gi + 2; tp = (tp > 255) ? 255 : tp;
      float4 nnA = ld4_xw(pA + tp), nnB = ld4_xw(pB + tp);
#pragma unroll
      for (int u = 0; u < 4; ++u) {
        float xa = (u==0)?curA.x:(u==1)?curA.y:(u==2)?curA.z:curA.w;
        float xb = (u==0)?curB.x:(u==1)?curB.y:(u==2)?curB.z:curB.w;
        v2f accA = whA2[0]*h2[0]; accA = whA2[1]*h2[1] + accA;
        accA = whA2[2]*h2[2] + accA; accA = whA2[3]*h2[3] + accA;
        v2f accB = whB2[0]*h2[0]; accB = whB2[1]*h2[1] + accB;
        accB = whB2[2]*h2[2] + accB; accB = whB2[3]*h2[3] + accB;
        float pa = (xa + accA.x) + accA.y;     // revolutions
        float pb = (xb + accB.x) + accB.y;
        float ccA = fmaf(0.5f, __builtin_amdgcn_cosf(pa), 0.5f);
        float ccB = fmaf(0.5f, __builtin_amdgcn_cosf(pb), 0.5f);

        // phase A: quad splats (wire cos^2, shared within gate)
        float C0 = dppf<0x00>(ccA), C1 = dppf<0x00>(ccB);
        float C5 = dppf<0x55>(ccA), C6 = dppf<0x55>(ccB);
        float C7 = dppf<0xAA>(ccA);

        // numerators + shared denominator
        float S0v = 1.f - C0, S1v = 1.f - C1;
        float P01 = C0 * C1, Q01 = S0v * S1v;
        float sel01 = isB7 ? Q01 : P01;        // = F0*F1
        float F7  = fmaf(s7, C7, o7);
        float F6A = fmaf(s6, C6, o6);
        float e7  = sel01 * F7;
        float dA  = C5 * F6A;
        float dB  = (1.f + dA) - (C5 + F6A);   // (1-C5)(1-F6A)
        float d56 = C5 * C6;
        float U0  = fmaf(2.f, d56, 1.f - (C5 + C6));
        float S7v = 1.f - C7;
        float T0  = fmaf(fmaf(2.f, C7, -1.f), U0, S7v);
        float sden = fmaf(P01 - Q01, T0, Q01);
        float es  = e7 * __builtin_amdgcn_rcpf(sden);
        float pnA = es * dA, pnB = es * dB;

        // phase C: cross-quad all-gather via direction-free DPP
        float rMA = dppf<0x140>(pnA);
        float rHA = dppf<0x141>(pnA);
        float r1A = dppf<0x1B>(rHA);           // (g^1, k)
        float r3A = dppf<0x1B>(rMA);           // (g^3, k)
        float r2A = dppf<0x141>(rMA);          // (g^2, k)
        float rMB = dppf<0x140>(pnB);
        float rHB = dppf<0x141>(pnB);
        float r1B = dppf<0x1B>(rHB);
        float r3B = dppf<0x1B>(rMB);
        float r2B = dppf<0x141>(rMB);

        float s32A = g0 ? r3A : r2A;  float s10A = g0 ? r1A : pnA;
        float sv1A = g0 ? pnA : r1A;  float s23A = g0 ? r2A : r3A;
        float fvA = g1 ? s32A : s10A;
        float uvA = g1 ? s10A : s32A;
        float ivA = g1 ? s23A : sv1A;
        float ovA = g1 ? sv1A : s23A;
        float s32B = g0 ? r3B : r2B;  float s10B = g0 ? r1B : pnB;
        float sv1B = g0 ? pnB : r1B;  float s23B = g0 ? r2B : r3B;
        float fvB = g1 ? s32B : s10B;
        float uvB = g1 ? s10B : s32B;
        float ivB = g1 ? s23B : sv1B;
        float ovB = g1 ? sv1B : s23B;

        // LSTM, index k (A) and k+4 (B)
        float t2A = uvA * uvA;
        float gvA = uvA * (t2A + 15.f) * __builtin_amdgcn_rcpf(fmaf(6.f, t2A, 15.f));
        cA = fmaf(fvA, cA, ivA * gvA);
        float eA = __builtin_amdgcn_exp2f(fminf(cA, 15.f) * 2.88539008f);
        hqA = ovA * fmaf(-2.f, __builtin_amdgcn_rcpf(eA + 1.f), 1.f);
        float t2B = uvB * uvB;
        float gvB = uvB * (t2B + 15.f) * __builtin_amdgcn_rcpf(fmaf(6.f, t2B, 15.f));
        cB = fmaf(fvB, cB, ivB * gvB);
        float eB = __builtin_amdgcn_exp2f(fminf(cB, 15.f) * 2.88539008f);
        hqB = ovB * fmaf(-2.f, __builtin_amdgcn_rcpf(eB + 1.f), 1.f);

        // phase D: quad splats -> h pairs (h0..h7)
        h2[0].x = dppf<0x00>(hqA); h2[0].y = dppf<0x55>(hqA);
        h2[1].x = dppf<0xAA>(hqA); h2[1].y = dppf<0xFF>(hqA);
        h2[2].x = dppf<0x00>(hqB); h2[2].y = dppf<0x55>(hqB);
        h2[3].x = dppf<0xAA>(hqB); h2[3].y = dppf<0xFF>(hqB);

        houtS[sg * 4 + u] = (g == 0) ? hqA : hqB;
      }
      curA = nxtA; nxtA = nnA;
      curB = nxtB; nxtB = nnB;
    }
    if (r < 8) {
      float* op = out + (size_t)Tb * (BATCH * NQ) + soff;
#pragma unroll
      for (int tt = 0; tt < 16; ++tt)
        op[(size_t)tt * (BATCH * NQ)] = houtS[tt];
    }
  }
  if (r < 8) {
    size_t o1 = (size_t)S_STEPS * BATCH * NQ + soff;
    out[o1] = (g == 0) ? hqA : hqB;                       // h_n
    out[o1 + (size_t)BATCH * NQ] = (g == 0) ? cA : cB;    // c_n
  }
}

extern "C" void kernel_launch(void* const* d_in, const int* in_sizes, int n_in,
                              void* d_out, int out_size, void* d_ws, size_t ws_size,
                              hipStream_t stream) {
  const float* x  = (const float*)d_in[0];
  const float* Wf = (const float*)d_in[1];
  const float* bf = (const float*)d_in[2];
  const float* Wi = (const float*)d_in[3];
  const float* bi = (const float*)d_in[4];
  const float* Wu = (const float*)d_in[5];
  const float* bu = (const float*)d_in[6];
  const float* Wo = (const float*)d_in[7];
  const float* bo = (const float*)d_in[8];
  float* xw  = (float*)d_ws;                                   // 10.49 MB compressed
  unsigned* cnt = (unsigned*)((char*)d_ws + CNT_BYTE_OFFSET);  // 64 slice counters
  float* out = (float*)d_out;

  hipMemsetAsync(cnt, 0, 64 * sizeof(unsigned), stream);
  qlstm_fused<<<32 + 8192, 512, 0, stream>>>(x, Wf, bf, Wi, bi, Wu, bu, Wo, bo,
                                             xw, cnt, out);
}

// Round 5
// 448.113 us; speedup vs baseline: 4.6546x; 4.6546x over previous
//
#include <hip/hip_runtime.h>

#define S_STEPS 1024
#define BATCH 128
#define NQ 8

// Compressed xw: only wire-planes {0,1,5,6,7} per gate are ever read by seq.
// Layout: xw[((b*4+g)*5 + widx)*1024 + t], 128*20*1024 floats = 10.49 MB.
#define XW_COMPRESSED_FLOATS (BATCH * 20 * 1024)

using v2f     = float __attribute__((ext_vector_type(2)));
using frag_ab = __attribute__((ext_vector_type(8))) short;   // 8 bf16
using frag_cd = __attribute__((ext_vector_type(4))) float;   // 4 fp32

#define INV2PI 0.15915494309189535f

// ---- helpers -----------------------------------------------------------
template<int CTRL>
__device__ __forceinline__ float dppf(float x) {   // DPP move (quad_perm / mirror / half_mirror)
  return __int_as_float(__builtin_amdgcn_update_dpp(0, __float_as_int(x), CTRL, 0xf, 0xf, true));
}
__device__ __forceinline__ short f2bf(float f) {   // fp32 -> bf16 (RNE)
  unsigned u = __float_as_uint(f);
  return (short)((u + 0x7FFFu + ((u >> 16) & 1u)) >> 16);
}
__device__ __forceinline__ float bf2f(short h) {
  return __uint_as_float(((unsigned)(unsigned short)h) << 16);
}

// ---- kernel 1: persistent MFMA GEMM.
// 1024 blocks x 512 thr (4 blocks/CU, all resident); each block loops 8 tiles.
// Theory: the ~200us residual across 3 prior pre structures is per-block fixed
// cost (8192 short-lived blocks); amortize it 8x. W frags/biases converted ONCE
// per block. Tile body identical to the verified R2 structure; barrier pattern
// [load xbuf | sync | frag+mfma+red-store | sync | reduce+store] makes
// cross-iteration xbuf/red reuse race-free.
__global__ __launch_bounds__(512) void qlstm_pre(
    const float* __restrict__ x,
    const float* __restrict__ Wf, const float* __restrict__ bf_,
    const float* __restrict__ Wi, const float* __restrict__ bi,
    const float* __restrict__ Wu, const float* __restrict__ bu,
    const float* __restrict__ Wo, const float* __restrict__ bo,
    float* __restrict__ xw)
{
  __shared__ float xbuf[16 * 256];   // 16 KB, 16B-slot swizzled
  __shared__ float red[8 * 520];     // 16.6 KB reduction planes (pitch 520)

  const int tid  = threadIdx.x;
  const int lane = tid & 63;
  const int wid  = tid >> 6;               // 0..7 = k-slice (wid*32 .. +32)
  const int m    = lane & 15;              // A-row (c within n-tile) / t offset
  const int kg   = lane >> 4;              // k group

  // ---- W fragments for this wave's k-slice (convert once per block)
  frag_ab awh[2], awl[2];
#pragma unroll
  for (int n = 0; n < 2; ++n) {
    const int c = n * 16 + m;
    const int g = c >> 3, w = c & 7;
    const float* Wg = (g == 0) ? Wf : (g == 1) ? Wi : (g == 2) ? Wu : Wo;
    const float* p = Wg + w * 264 + wid * 32 + kg * 8;
    float4 a  = *(const float4*)(p);
    float4 bq = *(const float4*)(p + 4);
    float vv[8] = {a.x, a.y, a.z, a.w, bq.x, bq.y, bq.z, bq.w};
#pragma unroll
    for (int j = 0; j < 8; ++j) {
      float wv = vv[j] * INV2PI;
      short h = f2bf(wv);
      awh[n][j] = h;
      awl[n][j] = f2bf(wv - bf2f(h));
    }
  }

  // ---- reduce-phase constants (c is fixed per thread; once per block)
  const int c  = tid >> 4, mm = tid & 15;
  const int v  = ((c >> 4) << 2) | (c & 3);          // n*4 + rho
  const int lp = (((c >> 2) & 3) << 4) | mm;         // kg*16 + m
  const int gg = c >> 3, ww = c & 7;
  const int widx = (ww==0)?0:(ww==1)?1:(ww==5)?2:(ww==6)?3:(ww==7)?4:-1;
  const float* bg = (gg == 0) ? bf_ : (gg == 1) ? bi : (gg == 2) ? bu : bo;
  const float bias = bg[ww] * INV2PI;

#pragma unroll 1
  for (int it = 0; it < 8; ++it) {
    const int pid = blockIdx.x * 8 + it;     // 0..8191
    const int t0i = pid >> 7;                // 0..63  (t-slice index)
    const int b   = pid & 127;               // 0..127
    const int t0  = t0i << 4;

    // coalesced x row load: thread T covers row r=T>>5, two 16B at slots s, 32+s
    {
      const int r = tid >> 5, s = tid & 31;
      const float* xrow = x + ((size_t)(t0 + r) * 128 + b) * 256;
      float4 f0 = *(const float4*)(xrow + s * 4);
      float4 f1 = *(const float4*)(xrow + 128 + s * 4);
      *(float4*)&xbuf[r * 256 + 4 * ((s)      ^ (r & 7))] = f0;
      *(float4*)&xbuf[r * 256 + 4 * ((32 + s) ^ (r & 7))] = f1;
    }
    __syncthreads();

    // x fragment from LDS (same swizzle), convert, 6 MFMA (bf16 hi/lo split)
    float4 v0 = *(const float4*)&xbuf[m * 256 + 4 * ((wid * 8 + kg * 2)     ^ (m & 7))];
    float4 v1 = *(const float4*)&xbuf[m * 256 + 4 * ((wid * 8 + kg * 2 + 1) ^ (m & 7))];
    float xf[8] = {v0.x, v0.y, v0.z, v0.w, v1.x, v1.y, v1.z, v1.w};
    frag_ab xh, xl;
#pragma unroll
    for (int j = 0; j < 8; ++j) {
      short h = f2bf(xf[j]);
      xh[j] = h;
      xl[j] = f2bf(xf[j] - bf2f(h));
    }

    frag_cd acc0 = {0.f, 0.f, 0.f, 0.f};
    frag_cd acc1 = {0.f, 0.f, 0.f, 0.f};
    acc0 = __builtin_amdgcn_mfma_f32_16x16x32_bf16(awh[0], xh, acc0, 0, 0, 0);
    acc0 = __builtin_amdgcn_mfma_f32_16x16x32_bf16(awl[0], xh, acc0, 0, 0, 0);
    acc0 = __builtin_amdgcn_mfma_f32_16x16x32_bf16(awh[0], xl, acc0, 0, 0, 0);
    acc1 = __builtin_amdgcn_mfma_f32_16x16x32_bf16(awh[1], xh, acc1, 0, 0, 0);
    acc1 = __builtin_amdgcn_mfma_f32_16x16x32_bf16(awl[1], xh, acc1, 0, 0, 0);
    acc1 = __builtin_amdgcn_mfma_f32_16x16x32_bf16(awh[1], xl, acc1, 0, 0, 0);

    // cross-wave K reduction: red[v=n*4+rho][wid][lane]
#pragma unroll
    for (int rho = 0; rho < 4; ++rho) {
      red[(rho)     * 520 + wid * 64 + lane] = acc0[rho];
      red[(4 + rho) * 520 + wid * 64 + lane] = acc1[rho];
    }
    __syncthreads();

    // reduce + bias + compressed store (only wire-planes {0,1,5,6,7})
    if (widx >= 0) {
      float sum = 0.f;
#pragma unroll
      for (int w8 = 0; w8 < 8; ++w8)
        sum += red[v * 520 + w8 * 64 + lp];
      xw[((size_t)((b * 4 + gg) * 5 + widx)) * 1024 + t0 + mm] = sum + bias;
    }
  }
}

// ---- kernel 2: recurrence. 32 blocks x 64 thr; 4 batches/wave, 16 lanes/batch.
// R2-verbatim compute (DPP phase C); only the xw plane indexing is remapped to
// the compressed 20-plane layout (mapping correctness proven in R4's pass).
__global__ __launch_bounds__(64) void qlstm_seq(
    const float* __restrict__ xw,
    const float* __restrict__ Wf, const float* __restrict__ Wi,
    const float* __restrict__ Wu, const float* __restrict__ Wo,
    float* __restrict__ out)
{
  const int lane = threadIdx.x;
  const int r = lane & 15, g = r >> 2, k = r & 3;
  const int b = blockIdx.x * 4 + (lane >> 4);
  const int B6 = (k >> 1) & 1, B7 = k & 1;
  const bool isB7 = (B7 != 0);
  const float s6 = B6 ? -1.f : 1.f,        o6 = B6 ? 1.f : 0.f;
  const float s7 = (B7^B6) ? -1.f : 1.f,   o7 = (B7^B6) ? 1.f : 0.f;
  const int wA = (k == 0) ? 0 : (k == 1) ? 5 : 7;        // W rows (uncompressed)
  const int wB = (k == 0) ? 1 : (k == 1) ? 6 : 7;
  const int widxA = (k == 0) ? 0 : (k == 1) ? 2 : 4;     // compressed xw planes
  const int widxB = (k == 0) ? 1 : (k == 1) ? 3 : 4;
  const bool g0 = (g & 1) != 0;
  const bool g1 = (g & 2) != 0;

  const float* Wg = (g == 0) ? Wf : (g == 1) ? Wi : (g == 2) ? Wu : Wo;
  v2f whA2[4], whB2[4];
#pragma unroll
  for (int j2 = 0; j2 < 4; ++j2) {
    whA2[j2] = (v2f){Wg[wA*264+256+2*j2] * INV2PI, Wg[wA*264+256+2*j2+1] * INV2PI};
    whB2[j2] = (v2f){Wg[wB*264+256+2*j2] * INV2PI, Wg[wB*264+256+2*j2+1] * INV2PI};
  }

  v2f h2[4];
#pragma unroll
  for (int j = 0; j < 4; ++j) h2[j] = (v2f){0.f, 0.f};
  float cA = 0.f, cB = 0.f, hqA = 0.f, hqB = 0.f;

  const float* bxw = xw + (size_t)b * 20480;
  const float4* pA = (const float4*)(bxw + (size_t)(g * 5 + widxA) * 1024);
  const float4* pB = (const float4*)(bxw + (size_t)(g * 5 + widxB) * 1024);
  float4 curA = pA[0], nxtA = pA[1];
  float4 curB = pB[0], nxtB = pB[1];

  const int soff = b * 8 + r;     // valid for r<8 (= g*4+k)
  float houtS[16];

#pragma unroll 1
  for (int Tb = 0; Tb < S_STEPS; Tb += 16) {
#pragma unroll
    for (int sg = 0; sg < 4; ++sg) {
      int gi = (Tb >> 2) + sg;
      int tp = gi + 2; tp = (tp > 255) ? 255 : tp;
      float4 nnA = pA[tp], nnB = pB[tp];
#pragma unroll
      for (int u = 0; u < 4; ++u) {
        float xa = (u==0)?curA.x:(u==1)?curA.y:(u==2)?curA.z:curA.w;
        float xb = (u==0)?curB.x:(u==1)?curB.y:(u==2)?curB.z:curB.w;
        v2f accA = whA2[0]*h2[0]; accA = whA2[1]*h2[1] + accA;
        accA = whA2[2]*h2[2] + accA; accA = whA2[3]*h2[3] + accA;
        v2f accB = whB2[0]*h2[0]; accB = whB2[1]*h2[1] + accB;
        accB = whB2[2]*h2[2] + accB; accB = whB2[3]*h2[3] + accB;
        float pa = (xa + accA.x) + accA.y;     // revolutions
        float pb = (xb + accB.x) + accB.y;
        float ccA = fmaf(0.5f, __builtin_amdgcn_cosf(pa), 0.5f);
        float ccB = fmaf(0.5f, __builtin_amdgcn_cosf(pb), 0.5f);

        // phase A: quad splats (wire cos^2, shared within gate)
        float C0 = dppf<0x00>(ccA), C1 = dppf<0x00>(ccB);
        float C5 = dppf<0x55>(ccA), C6 = dppf<0x55>(ccB);
        float C7 = dppf<0xAA>(ccA);

        // numerators + shared denominator
        float S0v = 1.f - C0, S1v = 1.f - C1;
        float P01 = C0 * C1, Q01 = S0v * S1v;
        float sel01 = isB7 ? Q01 : P01;        // = F0*F1
        float F7  = fmaf(s7, C7, o7);
        float F6A = fmaf(s6, C6, o6);
        float e7  = sel01 * F7;
        float dA  = C5 * F6A;
        float dB  = (1.f + dA) - (C5 + F6A);   // (1-C5)(1-F6A)
        float d56 = C5 * C6;
        float U0  = fmaf(2.f, d56, 1.f - (C5 + C6));
        float S7v = 1.f - C7;
        float T0  = fmaf(fmaf(2.f, C7, -1.f), U0, S7v);
        float sden = fmaf(P01 - Q01, T0, Q01);
        float es  = e7 * __builtin_amdgcn_rcpf(sden);
        float pnA = es * dA, pnB = es * dB;

        // phase C: cross-quad all-gather via direction-free DPP
        float rMA = dppf<0x140>(pnA);
        float rHA = dppf<0x141>(pnA);
        float r1A = dppf<0x1B>(rHA);           // (g^1, k)
        float r3A = dppf<0x1B>(rMA);           // (g^3, k)
        float r2A = dppf<0x141>(rMA);          // (g^2, k)
        float rMB = dppf<0x140>(pnB);
        float rHB = dppf<0x141>(pnB);
        float r1B = dppf<0x1B>(rHB);
        float r3B = dppf<0x1B>(rMB);
        float r2B = dppf<0x141>(rMB);

        float s32A = g0 ? r3A : r2A;  float s10A = g0 ? r1A : pnA;
        float sv1A = g0 ? pnA : r1A;  float s23A = g0 ? r2A : r3A;
        float fvA = g1 ? s32A : s10A;
        float uvA = g1 ? s10A : s32A;
        float ivA = g1 ? s23A : sv1A;
        float ovA = g1 ? sv1A : s23A;
        float s32B = g0 ? r3B : r2B;  float s10B = g0 ? r1B : pnB;
        float sv1B = g0 ? pnB : r1B;  float s23B = g0 ? r2B : r3B;
        float fvB = g1 ? s32B : s10B;
        float uvB = g1 ? s10B : s32B;
        float ivB = g1 ? s23B : sv1B;
        float ovB = g1 ? sv1B : s23B;

        // LSTM, index k (A) and k+4 (B)
        float t2A = uvA * uvA;
        float gvA = uvA * (t2A + 15.f) * __builtin_amdgcn_rcpf(fmaf(6.f, t2A, 15.f));
        cA = fmaf(fvA, cA, ivA * gvA);
        float eA = __builtin_amdgcn_exp2f(fminf(cA, 15.f) * 2.88539008f);
        hqA = ovA * fmaf(-2.f, __builtin_amdgcn_rcpf(eA + 1.f), 1.f);
        float t2B = uvB * uvB;
        float gvB = uvB * (t2B + 15.f) * __builtin_amdgcn_rcpf(fmaf(6.f, t2B, 15.f));
        cB = fmaf(fvB, cB, ivB * gvB);
        float eB = __builtin_amdgcn_exp2f(fminf(cB, 15.f) * 2.88539008f);
        hqB = ovB * fmaf(-2.f, __builtin_amdgcn_rcpf(eB + 1.f), 1.f);

        // phase D: quad splats -> h pairs (h0..h7)
        h2[0].x = dppf<0x00>(hqA); h2[0].y = dppf<0x55>(hqA);
        h2[1].x = dppf<0xAA>(hqA); h2[1].y = dppf<0xFF>(hqA);
        h2[2].x = dppf<0x00>(hqB); h2[2].y = dppf<0x55>(hqB);
        h2[3].x = dppf<0xAA>(hqB); h2[3].y = dppf<0xFF>(hqB);

        houtS[sg * 4 + u] = (g == 0) ? hqA : hqB;
      }
      curA = nxtA; nxtA = nnA;
      curB = nxtB; nxtB = nnB;
    }
    if (r < 8) {
      float* op = out + (size_t)Tb * (BATCH * NQ) + soff;
#pragma unroll
      for (int tt = 0; tt < 16; ++tt)
        op[(size_t)tt * (BATCH * NQ)] = houtS[tt];
    }
  }
  if (r < 8) {
    size_t o1 = (size_t)S_STEPS * BATCH * NQ + soff;
    out[o1] = (g == 0) ? hqA : hqB;                       // h_n
    out[o1 + (size_t)BATCH * NQ] = (g == 0) ? cA : cB;    // c_n
  }
}

extern "C" void kernel_launch(void* const* d_in, const int* in_sizes, int n_in,
                              void* d_out, int out_size, void* d_ws, size_t ws_size,
                              hipStream_t stream) {
  const float* x  = (const float*)d_in[0];
  const float* Wf = (const float*)d_in[1];
  const float* bf = (const float*)d_in[2];
  const float* Wi = (const float*)d_in[3];
  const float* bi = (const float*)d_in[4];
  const float* Wu = (const float*)d_in[5];
  const float* bu = (const float*)d_in[6];
  const float* Wo = (const float*)d_in[7];
  const float* bo = (const float*)d_in[8];
  float* xw  = (float*)d_ws;               // 10.49 MB compressed
  float* out = (float*)d_out;

  qlstm_pre<<<1024, 512, 0, stream>>>(x, Wf, bf, Wi, bi, Wu, bu, Wo, bo, xw);
  qlstm_seq<<<32, 64, 0, stream>>>(xw, Wf, Wi, Wu, Wo, out);
}